// Round 1
// baseline (2061.766 us; speedup 1.0000x reference)
//
#include <hip/hip_runtime.h>

#define N_NODES 100000
#define N_EDGES 1600000
#define NFEAT 128
#define NHID 64
#define NCLASS 16

// ---------- edge-index dtype detection ----------
// Reference creates int64 edge_index; harness docs suggest int32. Detect on
// device: if data is int64 (values < 2^31, little-endian), every odd u32 is 0.
__global__ void detect_kernel(const unsigned int* __restrict__ ei, int* __restrict__ flag) {
    __shared__ int any_nz;
    if (threadIdx.x == 0) any_nz = 0;
    __syncthreads();
    unsigned int v = ei[2 * threadIdx.x + 1];
    if (v != 0) any_nz = 1;
    __syncthreads();
    if (threadIdx.x == 0) *flag = any_nz;  // 1 => int32 data, 0 => int64 data
}

__global__ void convert_kernel(const void* __restrict__ ei, const int* __restrict__ flag,
                               int* __restrict__ src, int* __restrict__ dst) {
    int e = blockIdx.x * blockDim.x + threadIdx.x;
    if (e >= N_EDGES) return;
    if (*flag) {
        const int* p = (const int*)ei;
        src[e] = p[e];
        dst[e] = p[N_EDGES + e];
    } else {
        const long long* p = (const long long*)ei;
        src[e] = (int)p[e];
        dst[e] = (int)p[N_EDGES + e];
    }
}

// ---------- dense row GEMMs (W staged in LDS, 1 row per thread) ----------
__global__ __launch_bounds__(256) void gemm1_kernel(const float* __restrict__ X,
                                                    const float* __restrict__ W,
                                                    float* __restrict__ Y) {
    __shared__ float Ws[NFEAT * NHID];  // 32 KB
    for (int i = threadIdx.x; i < NFEAT * NHID; i += 256) Ws[i] = W[i];
    __syncthreads();
    int row = blockIdx.x * 256 + threadIdx.x;
    if (row >= N_NODES) return;
    float acc[NHID];
#pragma unroll
    for (int j = 0; j < NHID; ++j) acc[j] = 0.f;
    const float* xr = X + (size_t)row * NFEAT;
    for (int k = 0; k < NFEAT; k += 4) {
        float4 xv = *(const float4*)(xr + k);
#pragma unroll
        for (int j = 0; j < NHID; ++j) {
            acc[j] += xv.x * Ws[(k + 0) * NHID + j];
            acc[j] += xv.y * Ws[(k + 1) * NHID + j];
            acc[j] += xv.z * Ws[(k + 2) * NHID + j];
            acc[j] += xv.w * Ws[(k + 3) * NHID + j];
        }
    }
    float* yr = Y + (size_t)row * NHID;
#pragma unroll
    for (int j = 0; j < NHID; j += 4) {
        float4 o = make_float4(acc[j], acc[j + 1], acc[j + 2], acc[j + 3]);
        *(float4*)(yr + j) = o;
    }
}

__global__ __launch_bounds__(256) void gemm2_kernel(const float* __restrict__ H,
                                                    const float* __restrict__ W,
                                                    float* __restrict__ Y) {
    __shared__ float Ws[NHID * NCLASS];  // 4 KB
    for (int i = threadIdx.x; i < NHID * NCLASS; i += 256) Ws[i] = W[i];
    __syncthreads();
    int row = blockIdx.x * 256 + threadIdx.x;
    if (row >= N_NODES) return;
    float acc[NCLASS];
#pragma unroll
    for (int j = 0; j < NCLASS; ++j) acc[j] = 0.f;
    const float* hr = H + (size_t)row * NHID;
    for (int k = 0; k < NHID; k += 4) {
        float4 hv = *(const float4*)(hr + k);
        hv.x = fmaxf(hv.x, 0.f);  // relu applied to layer-1 output
        hv.y = fmaxf(hv.y, 0.f);
        hv.z = fmaxf(hv.z, 0.f);
        hv.w = fmaxf(hv.w, 0.f);
#pragma unroll
        for (int j = 0; j < NCLASS; ++j) {
            acc[j] += hv.x * Ws[(k + 0) * NCLASS + j];
            acc[j] += hv.y * Ws[(k + 1) * NCLASS + j];
            acc[j] += hv.z * Ws[(k + 2) * NCLASS + j];
            acc[j] += hv.w * Ws[(k + 3) * NCLASS + j];
        }
    }
    float* yr = Y + (size_t)row * NCLASS;
#pragma unroll
    for (int j = 0; j < NCLASS; j += 4) {
        float4 o = make_float4(acc[j], acc[j + 1], acc[j + 2], acc[j + 3]);
        *(float4*)(yr + j) = o;
    }
}

// ---------- edge scatter-add (atomic) ----------
// Layer 1: 16 lanes per edge, 4 feats per lane (NHID=64)
__global__ __launch_bounds__(256) void scatter1_kernel(const float* __restrict__ xw,
                                                       const int* __restrict__ src,
                                                       const int* __restrict__ dst,
                                                       const float* __restrict__ w,
                                                       float* __restrict__ h) {
    int tid = blockIdx.x * 256 + threadIdx.x;
    int e = tid >> 4;
    int c = (tid & 15) * 4;
    int s = src[e], d = dst[e];
    float we = w[e];
    float4 v = *(const float4*)(xw + (size_t)s * NHID + c);
    float* hp = h + (size_t)d * NHID + c;
    atomicAdd(hp + 0, we * v.x);
    atomicAdd(hp + 1, we * v.y);
    atomicAdd(hp + 2, we * v.z);
    atomicAdd(hp + 3, we * v.w);
}

// Layer 2: 4 lanes per edge, 4 feats per lane (NCLASS=16)
__global__ __launch_bounds__(256) void scatter2_kernel(const float* __restrict__ hw,
                                                       const int* __restrict__ src,
                                                       const int* __restrict__ dst,
                                                       const float* __restrict__ w,
                                                       float* __restrict__ out) {
    int tid = blockIdx.x * 256 + threadIdx.x;
    int e = tid >> 2;
    int c = (tid & 3) * 4;
    int s = src[e], d = dst[e];
    float we = w[e];
    float4 v = *(const float4*)(hw + (size_t)s * NCLASS + c);
    float* op = out + (size_t)d * NCLASS + c;
    atomicAdd(op + 0, we * v.x);
    atomicAdd(op + 1, we * v.y);
    atomicAdd(op + 2, we * v.z);
    atomicAdd(op + 3, we * v.w);
}

extern "C" void kernel_launch(void* const* d_in, const int* in_sizes, int n_in,
                              void* d_out, int out_size, void* d_ws, size_t ws_size,
                              hipStream_t stream) {
    const float* x  = (const float*)d_in[0];
    const void*  ei = d_in[1];
    const float* ew = (const float*)d_in[2];
    const float* W1 = (const float*)d_in[3];
    const float* W2 = (const float*)d_in[4];
    float* out = (float*)d_out;

    char* ws = (char*)d_ws;
    int*   flag = (int*)(ws + 0);
    int*   src  = (int*)(ws + 16);
    int*   dst  = (int*)(ws + 16 + 6400000);
    float* xw   = (float*)(ws + 16 + 12800000);            // [N, 64]
    float* h    = (float*)(ws + 16 + 12800000 + 25600000); // [N, 64]
    float* hw   = (float*)(ws + 16 + 12800000);            // reuse xw: [N, 16]

    detect_kernel<<<1, 256, 0, stream>>>((const unsigned int*)ei, flag);
    convert_kernel<<<(N_EDGES + 255) / 256, 256, 0, stream>>>(ei, flag, src, dst);

    gemm1_kernel<<<(N_NODES + 255) / 256, 256, 0, stream>>>(x, W1, xw);

    hipMemsetAsync(h, 0, (size_t)N_NODES * NHID * sizeof(float), stream);
    scatter1_kernel<<<(N_EDGES * 16) / 256, 256, 0, stream>>>(xw, src, dst, ew, h);

    gemm2_kernel<<<(N_NODES + 255) / 256, 256, 0, stream>>>(h, W2, hw);

    hipMemsetAsync(out, 0, (size_t)N_NODES * NCLASS * sizeof(float), stream);
    scatter2_kernel<<<(N_EDGES * 4) / 256, 256, 0, stream>>>(hw, src, dst, ew, out);
}

// Round 2
// 450.408 us; speedup vs baseline: 4.5776x; 4.5776x over previous
//
#include <hip/hip_runtime.h>

#define N_NODES 100000
#define N_EDGES 1600000
#define NFEAT 128
#define NHID 64
#define NCLASS 16
#define SCAN_TILE 1024
#define NB_SCAN ((N_NODES + SCAN_TILE - 1) / SCAN_TILE)  // 98

// ---------- edge-index dtype detection (int64 ref vs int32 harness) ----------
__global__ void detect_kernel(const unsigned int* __restrict__ ei, int* __restrict__ flag) {
    __shared__ int any_nz;
    if (threadIdx.x == 0) any_nz = 0;
    __syncthreads();
    unsigned int v = ei[2 * threadIdx.x + 1];
    if (v != 0) any_nz = 1;
    __syncthreads();
    if (threadIdx.x == 0) *flag = any_nz;  // 1 => int32 data, 0 => int64 data
}

__device__ __forceinline__ int load_idx(const void* ei, int flag, size_t pos) {
    return flag ? ((const int*)ei)[pos] : (int)((const long long*)ei)[pos];
}

// ---------- counting sort by dst: histogram -> scan -> fill ----------
__global__ __launch_bounds__(256) void hist_kernel(const void* __restrict__ ei,
                                                   const int* __restrict__ flag,
                                                   int* __restrict__ deg) {
    int e = blockIdx.x * 256 + threadIdx.x;
    if (e >= N_EDGES) return;
    int d = load_idx(ei, *flag, (size_t)N_EDGES + e);
    atomicAdd(&deg[d], 1);
}

// per-block inclusive scan of SCAN_TILE elements (4/thread), write block sums
__global__ __launch_bounds__(256) void scan1_kernel(const int* __restrict__ deg,
                                                    int* __restrict__ incl,
                                                    int* __restrict__ bsum) {
    __shared__ int lds[256];
    int t = threadIdx.x;
    int base = blockIdx.x * SCAN_TILE + t * 4;
    int a0 = (base + 0 < N_NODES) ? deg[base + 0] : 0;
    int a1 = (base + 1 < N_NODES) ? deg[base + 1] : 0;
    int a2 = (base + 2 < N_NODES) ? deg[base + 2] : 0;
    int a3 = (base + 3 < N_NODES) ? deg[base + 3] : 0;
    int s1 = a0 + a1, s2 = s1 + a2, s3 = s2 + a3;
    lds[t] = s3;
    __syncthreads();
    for (int off = 1; off < 256; off <<= 1) {
        int v = (t >= off) ? lds[t - off] : 0;
        __syncthreads();
        lds[t] += v;
        __syncthreads();
    }
    int prev = lds[t] - s3;  // exclusive over threads
    if (t == 255) bsum[blockIdx.x] = lds[255];
    if (base + 0 < N_NODES) incl[base + 0] = prev + a0;
    if (base + 1 < N_NODES) incl[base + 1] = prev + s1;
    if (base + 2 < N_NODES) incl[base + 2] = prev + s2;
    if (base + 3 < N_NODES) incl[base + 3] = prev + s3;
}

// single-block inclusive scan of the NB_SCAN block sums (in place)
__global__ __launch_bounds__(128) void scan2_kernel(int* __restrict__ bsum) {
    __shared__ int lds[128];
    int t = threadIdx.x;
    lds[t] = (t < NB_SCAN) ? bsum[t] : 0;
    __syncthreads();
    for (int off = 1; off < 128; off <<= 1) {
        int v = (t >= off) ? lds[t - off] : 0;
        __syncthreads();
        lds[t] += v;
        __syncthreads();
    }
    if (t < NB_SCAN) bsum[t] = lds[t];
    __syncthreads();
}

// finalize: exclusive row_ptr + cursor copy
__global__ __launch_bounds__(256) void scan3_kernel(const int* __restrict__ deg,
                                                    const int* __restrict__ incl,
                                                    const int* __restrict__ bsum,
                                                    int* __restrict__ row_ptr,
                                                    int* __restrict__ cursor) {
    int i = blockIdx.x * 256 + threadIdx.x;
    if (i == 0) row_ptr[N_NODES] = N_EDGES;
    if (i >= N_NODES) return;
    int b = i / SCAN_TILE;
    int add = (b > 0) ? bsum[b - 1] : 0;
    int excl = incl[i] + add - deg[i];
    row_ptr[i] = excl;
    cursor[i] = excl;
}

__global__ __launch_bounds__(256) void fill_kernel(const void* __restrict__ ei,
                                                   const int* __restrict__ flag,
                                                   const float* __restrict__ ew,
                                                   int* __restrict__ cursor,
                                                   int* __restrict__ e_src,
                                                   float* __restrict__ e_w) {
    int e = blockIdx.x * 256 + threadIdx.x;
    if (e >= N_EDGES) return;
    int f = *flag;
    int s = load_idx(ei, f, (size_t)e);
    int d = load_idx(ei, f, (size_t)N_EDGES + e);
    int pos = atomicAdd(&cursor[d], 1);
    e_src[pos] = s;
    e_w[pos] = ew[e];
}

// ---------- dense row GEMMs (W staged in LDS, 1 row per thread) ----------
__global__ __launch_bounds__(256) void gemm1_kernel(const float* __restrict__ X,
                                                    const float* __restrict__ W,
                                                    float* __restrict__ Y) {
    __shared__ float Ws[NFEAT * NHID];  // 32 KB
    for (int i = threadIdx.x; i < NFEAT * NHID; i += 256) Ws[i] = W[i];
    __syncthreads();
    int row = blockIdx.x * 256 + threadIdx.x;
    if (row >= N_NODES) return;
    float acc[NHID];
#pragma unroll
    for (int j = 0; j < NHID; ++j) acc[j] = 0.f;
    const float* xr = X + (size_t)row * NFEAT;
    for (int k = 0; k < NFEAT; k += 4) {
        float4 xv = *(const float4*)(xr + k);
#pragma unroll
        for (int j = 0; j < NHID; ++j) {
            acc[j] += xv.x * Ws[(k + 0) * NHID + j];
            acc[j] += xv.y * Ws[(k + 1) * NHID + j];
            acc[j] += xv.z * Ws[(k + 2) * NHID + j];
            acc[j] += xv.w * Ws[(k + 3) * NHID + j];
        }
    }
    float* yr = Y + (size_t)row * NHID;
#pragma unroll
    for (int j = 0; j < NHID; j += 4) {
        *(float4*)(yr + j) = make_float4(acc[j], acc[j + 1], acc[j + 2], acc[j + 3]);
    }
}

__global__ __launch_bounds__(256) void gemm2_kernel(const float* __restrict__ H,
                                                    const float* __restrict__ W,
                                                    float* __restrict__ Y) {
    __shared__ float Ws[NHID * NCLASS];  // 4 KB
    for (int i = threadIdx.x; i < NHID * NCLASS; i += 256) Ws[i] = W[i];
    __syncthreads();
    int row = blockIdx.x * 256 + threadIdx.x;
    if (row >= N_NODES) return;
    float acc[NCLASS];
#pragma unroll
    for (int j = 0; j < NCLASS; ++j) acc[j] = 0.f;
    const float* hr = H + (size_t)row * NHID;
    for (int k = 0; k < NHID; k += 4) {
        float4 hv = *(const float4*)(hr + k);  // relu already applied in agg1
#pragma unroll
        for (int j = 0; j < NCLASS; ++j) {
            acc[j] += hv.x * Ws[(k + 0) * NCLASS + j];
            acc[j] += hv.y * Ws[(k + 1) * NCLASS + j];
            acc[j] += hv.z * Ws[(k + 2) * NCLASS + j];
            acc[j] += hv.w * Ws[(k + 3) * NCLASS + j];
        }
    }
    float* yr = Y + (size_t)row * NCLASS;
#pragma unroll
    for (int j = 0; j < NCLASS; j += 4) {
        *(float4*)(yr + j) = make_float4(acc[j], acc[j + 1], acc[j + 2], acc[j + 3]);
    }
}

// ---------- CSR aggregation, no atomics ----------
// Layer 1: one wave per dst node, 64 lanes = 64 hidden features; relu fused.
__global__ __launch_bounds__(256) void agg1_kernel(const float* __restrict__ xw,
                                                   const int* __restrict__ row_ptr,
                                                   const int* __restrict__ e_src,
                                                   const float* __restrict__ e_w,
                                                   float* __restrict__ h) {
    int node = blockIdx.x * 4 + (threadIdx.x >> 6);
    int lane = threadIdx.x & 63;
    if (node >= N_NODES) return;
    int start = row_ptr[node], end = row_ptr[node + 1];
    float acc = 0.f;
    for (int i = start; i < end; ++i) {
        int s = e_src[i];
        float w = e_w[i];
        acc += w * xw[(size_t)s * NHID + lane];  // 256B coalesced row read
    }
    h[(size_t)node * NHID + lane] = fmaxf(acc, 0.f);
}

// Layer 2: one wave per dst node; lane = sub*16 + feat, 4 edges in flight,
// shfl_xor reduce across the 4 subgroups.
__global__ __launch_bounds__(256) void agg2_kernel(const float* __restrict__ hw,
                                                   const int* __restrict__ row_ptr,
                                                   const int* __restrict__ e_src,
                                                   const float* __restrict__ e_w,
                                                   float* __restrict__ out) {
    int node = blockIdx.x * 4 + (threadIdx.x >> 6);
    int lane = threadIdx.x & 63;
    int f = lane & 15;
    int sub = lane >> 4;
    if (node >= N_NODES) return;
    int start = row_ptr[node], end = row_ptr[node + 1];
    float acc = 0.f;
    for (int i = start + sub; i < end; i += 4) {
        acc += e_w[i] * hw[(size_t)e_src[i] * NCLASS + f];
    }
    acc += __shfl_xor(acc, 16, 64);
    acc += __shfl_xor(acc, 32, 64);
    if (sub == 0) out[(size_t)node * NCLASS + f] = acc;
}

extern "C" void kernel_launch(void* const* d_in, const int* in_sizes, int n_in,
                              void* d_out, int out_size, void* d_ws, size_t ws_size,
                              hipStream_t stream) {
    const float* x  = (const float*)d_in[0];
    const void*  ei = d_in[1];
    const float* ew = (const float*)d_in[2];
    const float* W1 = (const float*)d_in[3];
    const float* W2 = (const float*)d_in[4];
    float* out = (float*)d_out;

    char* ws = (char*)d_ws;
    size_t off = 0;
    auto take = [&](size_t bytes) {
        char* p = ws + off;
        off += (bytes + 511) & ~(size_t)511;
        return p;
    };
    int*   flag    = (int*)take(4);
    int*   deg     = (int*)take((size_t)N_NODES * 4);
    int*   incl    = (int*)take((size_t)N_NODES * 4);
    int*   bsum    = (int*)take((size_t)NB_SCAN * 4);
    int*   row_ptr = (int*)take((size_t)(N_NODES + 1) * 4);
    int*   cursor  = (int*)take((size_t)N_NODES * 4);
    int*   e_src   = (int*)take((size_t)N_EDGES * 4);
    float* e_w     = (float*)take((size_t)N_EDGES * 4);
    float* xw      = (float*)take((size_t)N_NODES * NHID * 4);
    float* h       = (float*)take((size_t)N_NODES * NHID * 4);
    float* hw      = xw;  // reuse: xw dead after agg1

    detect_kernel<<<1, 256, 0, stream>>>((const unsigned int*)ei, flag);
    hipMemsetAsync(deg, 0, (size_t)N_NODES * 4, stream);
    hist_kernel<<<(N_EDGES + 255) / 256, 256, 0, stream>>>(ei, flag, deg);
    scan1_kernel<<<NB_SCAN, 256, 0, stream>>>(deg, incl, bsum);
    scan2_kernel<<<1, 128, 0, stream>>>(bsum);
    scan3_kernel<<<(N_NODES + 255) / 256, 256, 0, stream>>>(deg, incl, bsum, row_ptr, cursor);
    fill_kernel<<<(N_EDGES + 255) / 256, 256, 0, stream>>>(ei, flag, ew, cursor, e_src, e_w);

    gemm1_kernel<<<(N_NODES + 255) / 256, 256, 0, stream>>>(x, W1, xw);
    agg1_kernel<<<(N_NODES + 3) / 4, 256, 0, stream>>>(xw, row_ptr, e_src, e_w, h);
    gemm2_kernel<<<(N_NODES + 255) / 256, 256, 0, stream>>>(h, W2, hw);
    agg2_kernel<<<(N_NODES + 3) / 4, 256, 0, stream>>>(hw, row_ptr, e_src, e_w, out);
}

// Round 3
// 349.317 us; speedup vs baseline: 5.9023x; 1.2894x over previous
//
#include <hip/hip_runtime.h>

#define N_NODES 100000
#define N_EDGES 1600000
#define NFEAT 128
#define NHID 64
#define NCLASS 16
#define SCAN_TILE 1024
#define NB_SCAN ((N_NODES + SCAN_TILE - 1) / SCAN_TILE)  // 98

typedef unsigned int u32;

// round-to-nearest-even f32 -> bf16, packed pair (a in low, b in high)
__device__ __forceinline__ u32 pack_bf16(float a, float b) {
    u32 ua = __float_as_uint(a);
    u32 ub = __float_as_uint(b);
    ua = (ua + 0x7fffu + ((ua >> 16) & 1u)) >> 16;
    ub = (ub + 0x7fffu + ((ub >> 16) & 1u)) >> 16;
    return ua | (ub << 16);
}
__device__ __forceinline__ float bf16_lo(u32 u) { return __uint_as_float(u << 16); }
__device__ __forceinline__ float bf16_hi(u32 u) { return __uint_as_float(u & 0xffff0000u); }

// ---------- edge-index dtype detection (int64 ref vs int32 harness) ----------
__global__ void detect_kernel(const u32* __restrict__ ei, int* __restrict__ flag) {
    __shared__ int any_nz;
    if (threadIdx.x == 0) any_nz = 0;
    __syncthreads();
    u32 v = ei[2 * threadIdx.x + 1];
    if (v != 0) any_nz = 1;
    __syncthreads();
    if (threadIdx.x == 0) *flag = any_nz;  // 1 => int32 data, 0 => int64 data
}

__device__ __forceinline__ int load_idx(const void* ei, int flag, size_t pos) {
    return flag ? ((const int*)ei)[pos] : (int)((const long long*)ei)[pos];
}

// ---------- counting sort by dst: histogram -> scan -> fill ----------
__global__ __launch_bounds__(256) void hist_kernel(const void* __restrict__ ei,
                                                   const int* __restrict__ flag,
                                                   int* __restrict__ deg) {
    int e = blockIdx.x * 256 + threadIdx.x;
    if (e >= N_EDGES) return;
    int d = load_idx(ei, *flag, (size_t)N_EDGES + e);
    atomicAdd(&deg[d], 1);
}

__global__ __launch_bounds__(256) void scan1_kernel(const int* __restrict__ deg,
                                                    int* __restrict__ incl,
                                                    int* __restrict__ bsum) {
    __shared__ int lds[256];
    int t = threadIdx.x;
    int base = blockIdx.x * SCAN_TILE + t * 4;
    int a0 = (base + 0 < N_NODES) ? deg[base + 0] : 0;
    int a1 = (base + 1 < N_NODES) ? deg[base + 1] : 0;
    int a2 = (base + 2 < N_NODES) ? deg[base + 2] : 0;
    int a3 = (base + 3 < N_NODES) ? deg[base + 3] : 0;
    int s1 = a0 + a1, s2 = s1 + a2, s3 = s2 + a3;
    lds[t] = s3;
    __syncthreads();
    for (int off = 1; off < 256; off <<= 1) {
        int v = (t >= off) ? lds[t - off] : 0;
        __syncthreads();
        lds[t] += v;
        __syncthreads();
    }
    int prev = lds[t] - s3;
    if (t == 255) bsum[blockIdx.x] = lds[255];
    if (base + 0 < N_NODES) incl[base + 0] = prev + a0;
    if (base + 1 < N_NODES) incl[base + 1] = prev + s1;
    if (base + 2 < N_NODES) incl[base + 2] = prev + s2;
    if (base + 3 < N_NODES) incl[base + 3] = prev + s3;
}

__global__ __launch_bounds__(128) void scan2_kernel(int* __restrict__ bsum) {
    __shared__ int lds[128];
    int t = threadIdx.x;
    lds[t] = (t < NB_SCAN) ? bsum[t] : 0;
    __syncthreads();
    for (int off = 1; off < 128; off <<= 1) {
        int v = (t >= off) ? lds[t - off] : 0;
        __syncthreads();
        lds[t] += v;
        __syncthreads();
    }
    if (t < NB_SCAN) bsum[t] = lds[t];
}

__global__ __launch_bounds__(256) void scan3_kernel(const int* __restrict__ deg,
                                                    const int* __restrict__ incl,
                                                    const int* __restrict__ bsum,
                                                    int* __restrict__ row_ptr,
                                                    int* __restrict__ cursor) {
    int i = blockIdx.x * 256 + threadIdx.x;
    if (i == 0) row_ptr[N_NODES] = N_EDGES;
    if (i >= N_NODES) return;
    int b = i / SCAN_TILE;
    int add = (b > 0) ? bsum[b - 1] : 0;
    int excl = incl[i] + add - deg[i];
    row_ptr[i] = excl;
    cursor[i] = excl;
}

__global__ __launch_bounds__(256) void fill_kernel(const void* __restrict__ ei,
                                                   const int* __restrict__ flag,
                                                   const float* __restrict__ ew,
                                                   int* __restrict__ cursor,
                                                   int2* __restrict__ ep) {
    int e = blockIdx.x * 256 + threadIdx.x;
    if (e >= N_EDGES) return;
    int f = *flag;
    int s = load_idx(ei, f, (size_t)e);
    int d = load_idx(ei, f, (size_t)N_EDGES + e);
    int pos = atomicAdd(&cursor[d], 1);
    ep[pos] = make_int2(s, __float_as_int(ew[e]));
}

// ---------- dense row GEMMs (W staged in LDS, 1 row per thread) ----------
// gemm1: X[N,128] fp32 @ W1[128,64] -> xwb packed bf16 [N, 32 u32]
__global__ __launch_bounds__(256) void gemm1_kernel(const float* __restrict__ X,
                                                    const float* __restrict__ W,
                                                    u32* __restrict__ Y) {
    __shared__ float Ws[NFEAT * NHID];  // 32 KB
    for (int i = threadIdx.x; i < NFEAT * NHID; i += 256) Ws[i] = W[i];
    __syncthreads();
    int row = blockIdx.x * 256 + threadIdx.x;
    if (row >= N_NODES) return;
    float acc[NHID];
#pragma unroll
    for (int j = 0; j < NHID; ++j) acc[j] = 0.f;
    const float* xr = X + (size_t)row * NFEAT;
    for (int k = 0; k < NFEAT; k += 4) {
        float4 xv = *(const float4*)(xr + k);
#pragma unroll
        for (int j = 0; j < NHID; ++j) {
            acc[j] += xv.x * Ws[(k + 0) * NHID + j];
            acc[j] += xv.y * Ws[(k + 1) * NHID + j];
            acc[j] += xv.z * Ws[(k + 2) * NHID + j];
            acc[j] += xv.w * Ws[(k + 3) * NHID + j];
        }
    }
    u32* yr = Y + (size_t)row * (NHID / 2);
#pragma unroll
    for (int m = 0; m < NHID / 2; m += 4) {
        uint4 o;
        o.x = pack_bf16(acc[2 * m + 0], acc[2 * m + 1]);
        o.y = pack_bf16(acc[2 * m + 2], acc[2 * m + 3]);
        o.z = pack_bf16(acc[2 * m + 4], acc[2 * m + 5]);
        o.w = pack_bf16(acc[2 * m + 6], acc[2 * m + 7]);
        *(uint4*)(yr + m) = o;
    }
}

// gemm2: h[N,64] fp32 @ W2[64,16] -> hwb packed bf16 [N, 8 u32]
__global__ __launch_bounds__(256) void gemm2_kernel(const float* __restrict__ H,
                                                    const float* __restrict__ W,
                                                    u32* __restrict__ Y) {
    __shared__ float Ws[NHID * NCLASS];  // 4 KB
    for (int i = threadIdx.x; i < NHID * NCLASS; i += 256) Ws[i] = W[i];
    __syncthreads();
    int row = blockIdx.x * 256 + threadIdx.x;
    if (row >= N_NODES) return;
    float acc[NCLASS];
#pragma unroll
    for (int j = 0; j < NCLASS; ++j) acc[j] = 0.f;
    const float* hr = H + (size_t)row * NHID;
    for (int k = 0; k < NHID; k += 4) {
        float4 hv = *(const float4*)(hr + k);
#pragma unroll
        for (int j = 0; j < NCLASS; ++j) {
            acc[j] += hv.x * Ws[(k + 0) * NCLASS + j];
            acc[j] += hv.y * Ws[(k + 1) * NCLASS + j];
            acc[j] += hv.z * Ws[(k + 2) * NCLASS + j];
            acc[j] += hv.w * Ws[(k + 3) * NCLASS + j];
        }
    }
    u32* yr = Y + (size_t)row * (NCLASS / 2);
    uint4 o0, o1;
    o0.x = pack_bf16(acc[0], acc[1]);
    o0.y = pack_bf16(acc[2], acc[3]);
    o0.z = pack_bf16(acc[4], acc[5]);
    o0.w = pack_bf16(acc[6], acc[7]);
    o1.x = pack_bf16(acc[8], acc[9]);
    o1.y = pack_bf16(acc[10], acc[11]);
    o1.z = pack_bf16(acc[12], acc[13]);
    o1.w = pack_bf16(acc[14], acc[15]);
    *(uint4*)(yr + 0) = o0;
    *(uint4*)(yr + 4) = o1;
}

// ---------- CSR aggregation, no atomics ----------
// Layer 1: half-wave (32 lanes) per node, lane owns 2 packed feats;
// 4-deep edge unroll -> 4 gathers in flight. relu fused. h written fp32.
__global__ __launch_bounds__(256) void agg1_kernel(const u32* __restrict__ xwb,
                                                   const int* __restrict__ row_ptr,
                                                   const int2* __restrict__ ep,
                                                   float* __restrict__ h) {
    int t = blockIdx.x * 256 + threadIdx.x;
    int node = t >> 5;
    int ln = t & 31;
    if (node >= N_NODES) return;
    int start = row_ptr[node], end = row_ptr[node + 1];
    float a0x = 0.f, a0y = 0.f, a1x = 0.f, a1y = 0.f;
    float a2x = 0.f, a2y = 0.f, a3x = 0.f, a3y = 0.f;
    int i = start;
    for (; i + 4 <= end; i += 4) {
        int2 p0 = ep[i + 0];
        int2 p1 = ep[i + 1];
        int2 p2 = ep[i + 2];
        int2 p3 = ep[i + 3];
        u32 u0 = xwb[(size_t)p0.x * 32 + ln];
        u32 u1 = xwb[(size_t)p1.x * 32 + ln];
        u32 u2 = xwb[(size_t)p2.x * 32 + ln];
        u32 u3 = xwb[(size_t)p3.x * 32 + ln];
        float w0 = __int_as_float(p0.y), w1 = __int_as_float(p1.y);
        float w2 = __int_as_float(p2.y), w3 = __int_as_float(p3.y);
        a0x += w0 * bf16_lo(u0); a0y += w0 * bf16_hi(u0);
        a1x += w1 * bf16_lo(u1); a1y += w1 * bf16_hi(u1);
        a2x += w2 * bf16_lo(u2); a2y += w2 * bf16_hi(u2);
        a3x += w3 * bf16_lo(u3); a3y += w3 * bf16_hi(u3);
    }
    for (; i < end; ++i) {
        int2 p0 = ep[i];
        u32 u0 = xwb[(size_t)p0.x * 32 + ln];
        float w0 = __int_as_float(p0.y);
        a0x += w0 * bf16_lo(u0); a0y += w0 * bf16_hi(u0);
    }
    float sx = (a0x + a1x) + (a2x + a3x);
    float sy = (a0y + a1y) + (a2y + a3y);
    *(float2*)(h + (size_t)node * NHID + 2 * ln) =
        make_float2(fmaxf(sx, 0.f), fmaxf(sy, 0.f));
}

// Layer 2: one wave per node; lane = sub*8 + p, p owns 2 packed feats,
// 8 edges in flight across subs, shfl_xor reduce.
__global__ __launch_bounds__(256) void agg2_kernel(const u32* __restrict__ hwb,
                                                   const int* __restrict__ row_ptr,
                                                   const int2* __restrict__ ep,
                                                   float* __restrict__ out) {
    int t = blockIdx.x * 256 + threadIdx.x;
    int node = t >> 6;
    int lane = t & 63;
    int p = lane & 7;
    int sub = lane >> 3;
    if (node >= N_NODES) return;
    int start = row_ptr[node], end = row_ptr[node + 1];
    float ax = 0.f, ay = 0.f;
    for (int i = start + sub; i < end; i += 8) {
        int2 pr = ep[i];
        u32 u = hwb[(size_t)pr.x * 8 + p];
        float w = __int_as_float(pr.y);
        ax += w * bf16_lo(u);
        ay += w * bf16_hi(u);
    }
    ax += __shfl_xor(ax, 8, 64);  ay += __shfl_xor(ay, 8, 64);
    ax += __shfl_xor(ax, 16, 64); ay += __shfl_xor(ay, 16, 64);
    ax += __shfl_xor(ax, 32, 64); ay += __shfl_xor(ay, 32, 64);
    if (sub == 0) *(float2*)(out + (size_t)node * NCLASS + 2 * p) = make_float2(ax, ay);
}

extern "C" void kernel_launch(void* const* d_in, const int* in_sizes, int n_in,
                              void* d_out, int out_size, void* d_ws, size_t ws_size,
                              hipStream_t stream) {
    const float* x  = (const float*)d_in[0];
    const void*  ei = d_in[1];
    const float* ew = (const float*)d_in[2];
    const float* W1 = (const float*)d_in[3];
    const float* W2 = (const float*)d_in[4];
    float* out = (float*)d_out;

    char* ws = (char*)d_ws;
    size_t off = 0;
    auto take = [&](size_t bytes) {
        char* p = ws + off;
        off += (bytes + 511) & ~(size_t)511;
        return p;
    };
    int*   flag    = (int*)take(4);
    int*   deg     = (int*)take((size_t)N_NODES * 4);
    int*   incl    = (int*)take((size_t)N_NODES * 4);
    int*   bsum    = (int*)take((size_t)NB_SCAN * 4);
    int*   row_ptr = (int*)take((size_t)(N_NODES + 1) * 4);
    int*   cursor  = (int*)take((size_t)N_NODES * 4);
    int2*  ep      = (int2*)take((size_t)N_EDGES * 8);
    u32*   xwb     = (u32*)take((size_t)N_NODES * (NHID / 2) * 4);  // bf16 packed
    float* h       = (float*)take((size_t)N_NODES * NHID * 4);
    u32*   hwb     = xwb;  // reuse: xwb dead after agg1 (3.2 MB <= 12.8 MB)

    detect_kernel<<<1, 256, 0, stream>>>((const u32*)ei, flag);
    hipMemsetAsync(deg, 0, (size_t)N_NODES * 4, stream);
    hist_kernel<<<(N_EDGES + 255) / 256, 256, 0, stream>>>(ei, flag, deg);
    scan1_kernel<<<NB_SCAN, 256, 0, stream>>>(deg, incl, bsum);
    scan2_kernel<<<1, 128, 0, stream>>>(bsum);
    scan3_kernel<<<(N_NODES + 255) / 256, 256, 0, stream>>>(deg, incl, bsum, row_ptr, cursor);
    fill_kernel<<<(N_EDGES + 255) / 256, 256, 0, stream>>>(ei, flag, ew, cursor, ep);

    gemm1_kernel<<<(N_NODES + 255) / 256, 256, 0, stream>>>(x, W1, xwb);
    agg1_kernel<<<(N_NODES * 32 + 255) / 256, 256, 0, stream>>>(xwb, row_ptr, ep, h);
    gemm2_kernel<<<(N_NODES + 255) / 256, 256, 0, stream>>>(h, W2, hwb);
    agg2_kernel<<<(N_NODES * 64 + 255) / 256, 256, 0, stream>>>(hwb, row_ptr, ep, out);
}